// Round 1
// baseline (693.199 us; speedup 1.0000x reference)
//
#include <hip/hip_runtime.h>

#define G 8192
#define B 32
#define O 128
#define NBLK 4096              // B * (G/64)
#define NTOT 262144.0f         // B*G

__device__ __forceinline__ float lrelu(float v) { return v >= 0.f ? v : 0.1f * v; }

// WeffT[k][o] = W[o][k] + W[o][K+k]   (transposed so per-k rows are contiguous for s_load)
__global__ void prep_w(const float* __restrict__ W, int ldw, int K, float* __restrict__ Wt) {
    int idx = blockIdx.x * 256 + threadIdx.x;
    if (idx >= K * O) return;
    int k = idx >> 7, o = idx & 127;
    Wt[k * O + o] = W[o * ldw + k] + W[o * ldw + K + k];
}

// bias0[b][o] = -sum_c Wb1[o][c] * features[b][c][0]
__global__ void bias0_first(const float* __restrict__ X, const float* __restrict__ W,
                            float* __restrict__ bias) {
    __shared__ float x0[64];
    int b = blockIdx.x, o = threadIdx.x;
    if (o < 64) x0[o] = X[((size_t)b * 64 + o) * G];
    __syncthreads();
    float acc = 0.f;
    for (int c = 0; c < 64; ++c) acc += W[o * 131 + 64 + c] * x0[c];
    bias[b * O + o] = -acc;
}

// bias0 for layers 2..4: input column g=0 is lrelu(a*y+c)
__global__ void bias0_next(const float* __restrict__ Y, const float* __restrict__ A,
                           const float* __restrict__ Cc, const float* __restrict__ W,
                           float* __restrict__ bias) {
    __shared__ float xn[128];
    int b = blockIdx.x, o = threadIdx.x;
    float v = Y[((size_t)b * O + o) * G];
    xn[o] = lrelu(A[o] * v + Cc[o]);
    __syncthreads();
    float acc = 0.f;
    for (int c = 0; c < 128; ++c) acc += W[o * 259 + 128 + c] * xn[c];
    bias[b * O + o] = -acc;
}

// Main layer kernel: tile O=128 x Gt=64. lane<->g column, wave<->32 channels.
// Writes raw y (pre-BN) and per-block (sum, sumsq) partials.
template<int K, bool NORM>
__global__ __launch_bounds__(256, 4) void edge_main(
    const float* __restrict__ Xin,   // [B][K][G]
    float* __restrict__ Yout,        // [B][O][G]  (may alias Xin: column-local, staged first)
    const float* __restrict__ Wt,    // [K][O] effective weights, transposed
    const float* __restrict__ W,     // original [O][ldw] (for the 3 ev weights)
    int ldw,
    const float* __restrict__ bias,  // [B][O]
    const float* __restrict__ A, const float* __restrict__ Cc,   // input norm (NORM only)
    const float* __restrict__ EV,    // [B][3][G]
    float* __restrict__ part)        // [NBLK][256]: [.][0:128]=sum, [.][128:256]=sumsq
{
    __shared__ float lds[128 * 68];  // staging rows stride 68 (16B-aligned, 2-way max); stats stride 65
    const int tid  = threadIdx.x;
    const int lane = tid & 63;
    const int wave = tid >> 6;
    const int gt   = blockIdx.x;     // 0..127
    const int b    = blockIdx.y;     // 0..31
    const int g0   = gt * 64;
    const int bid  = b * 128 + gt;
    const int ob   = __builtin_amdgcn_readfirstlane(wave * 32);

    // ---- stage input tile [K][64] into LDS (normalize+lrelu on the fly for layers>=2)
    for (int f = tid; f < K * 16; f += 256) {
        int k = f >> 4, c4 = (f & 15) * 4;
        const float* src = Xin + ((size_t)b * K + k) * G + g0 + c4;
        float4 v = *reinterpret_cast<const float4*>(src);
        if (NORM) {
            float a = A[k], cc = Cc[k];
            v.x = lrelu(a * v.x + cc);
            v.y = lrelu(a * v.y + cc);
            v.z = lrelu(a * v.z + cc);
            v.w = lrelu(a * v.w + cc);
        }
        *reinterpret_cast<float4*>(&lds[k * 68 + c4]) = v;
    }
    __syncthreads();

    // ---- init acc with bias0 + ev contribution (W reads are wave-uniform -> scalar)
    float acc[32];
    float e0 = EV[((size_t)b * 3 + 0) * G + g0 + lane];
    float e1 = EV[((size_t)b * 3 + 1) * G + g0 + lane];
    float e2 = EV[((size_t)b * 3 + 2) * G + g0 + lane];
#pragma unroll
    for (int i = 0; i < 32; ++i) {
        int o = ob + i;
        const float* wr = W + o * ldw + 2 * K;
        acc[i] = bias[b * O + o] + wr[0] * e0 + wr[1] * e1 + wr[2] * e2;
    }

    // ---- main GEMM loop: per k, 1 conflict-free LDS read + 32 FMA with scalar W
#pragma unroll 2
    for (int k = 0; k < K; ++k) {
        float xv = lds[k * 68 + lane];
        const float* wk = Wt + k * O + ob;
#pragma unroll
        for (int i = 0; i < 32; ++i) acc[i] += wk[i] * xv;
    }

    // ---- write raw y (coalesced, 256B per store)
#pragma unroll
    for (int i = 0; i < 32; ++i)
        Yout[((size_t)b * O + ob + i) * G + g0 + lane] = acc[i];

    __syncthreads();   // all waves done reading staging region before we overwrite it
    // dump this wave's 32x64 sub-tile, rows stride 65 (conflict-free strided reads)
#pragma unroll
    for (int i = 0; i < 32; ++i) lds[(ob + i) * 65 + lane] = acc[i];
    // each wave reads back only its own rows -> no barrier needed
    int r = ob + (lane & 31);
    bool sq = lane >= 32;
    float s = 0.f;
    for (int j = 0; j < 64; ++j) {
        float v = lds[r * 65 + j];
        s += sq ? v * v : v;
    }
    part[bid * 256 + (sq ? 128 : 0) + r] = s;
}

// per-channel: reduce partials -> a = gamma*rsqrt(var+eps), c = beta - mean*a
__global__ void finalize(const float* __restrict__ part, const float* __restrict__ gamma,
                         const float* __restrict__ beta, float* __restrict__ A,
                         float* __restrict__ Cc) {
    __shared__ float rs[256], rq[256];
    int o = blockIdx.x, t = threadIdx.x;
    float s = 0.f, q = 0.f;
    for (int bid = t; bid < NBLK; bid += 256) {
        s += part[bid * 256 + o];
        q += part[bid * 256 + 128 + o];
    }
    rs[t] = s; rq[t] = q;
    __syncthreads();
    for (int w = 128; w > 0; w >>= 1) {
        if (t < w) { rs[t] += rs[t + w]; rq[t] += rq[t + w]; }
        __syncthreads();
    }
    if (t == 0) {
        float mean = rs[0] / NTOT;
        float var  = rq[0] / NTOT - mean * mean;
        float a = gamma[o] * rsqrtf(var + 1e-5f);
        A[o]  = a;
        Cc[o] = beta[o] - mean * a;
    }
}

// out[b][o] = max_g lrelu(a*y+c)
__global__ void maxout(const float* __restrict__ Y, const float* __restrict__ A,
                       const float* __restrict__ Cc, float* __restrict__ out) {
    int w    = blockIdx.x * 4 + (threadIdx.x >> 6);  // 0..4095
    int lane = threadIdx.x & 63;
    int b = w >> 7, o = w & 127;
    float a = A[o], cc = Cc[o];
    const float* row = Y + ((size_t)b * O + o) * G;
    float m = -3.4e38f;
    for (int j = lane * 4; j < G; j += 256) {
        float4 v = *reinterpret_cast<const float4*>(row + j);
        m = fmaxf(m, fmaxf(fmaxf(lrelu(a * v.x + cc), lrelu(a * v.y + cc)),
                           fmaxf(lrelu(a * v.z + cc), lrelu(a * v.w + cc))));
    }
    for (int d = 32; d > 0; d >>= 1) m = fmaxf(m, __shfl_down(m, d, 64));
    if (lane == 0) out[b * O + o] = m;
}

extern "C" void kernel_launch(void* const* d_in, const int* in_sizes, int n_in,
                              void* d_out, int out_size, void* d_ws, size_t ws_size,
                              hipStream_t stream) {
    const float* feat = (const float*)d_in[0];
    const float* ev   = (const float*)d_in[1];
    const float* W1   = (const float*)d_in[2];
    const float* W2   = (const float*)d_in[3];
    const float* W3   = (const float*)d_in[4];
    const float* W4   = (const float*)d_in[5];
    const float* g1   = (const float*)d_in[6];
    const float* b1   = (const float*)d_in[7];
    const float* g2   = (const float*)d_in[8];
    const float* b2   = (const float*)d_in[9];
    const float* g3   = (const float*)d_in[10];
    const float* b3   = (const float*)d_in[11];
    const float* g4   = (const float*)d_in[12];
    const float* b4   = (const float*)d_in[13];

    float* ws   = (float*)d_ws;
    float* y    = ws;                       // 33,554,432 floats (128 MB)
    float* wt1  = ws + 33554432;            // 8192
    float* wt2  = wt1 + 8192;               // 16384
    float* wt3  = wt2 + 16384;              // 16384
    float* wt4  = wt3 + 16384;              // 16384
    float* bias = wt4 + 16384;              // 4096
    float* Aar  = bias + 4096;              // 128
    float* Car  = Aar + 128;                // 128
    float* part = Car + 128;                // 1,048,576 floats (4 MB)

    dim3 mg(128, 32);
    prep_w<<<32, 256, 0, stream>>>(W1, 131, 64, wt1);
    prep_w<<<64, 256, 0, stream>>>(W2, 259, 128, wt2);
    prep_w<<<64, 256, 0, stream>>>(W3, 259, 128, wt3);
    prep_w<<<64, 256, 0, stream>>>(W4, 259, 128, wt4);
    bias0_first<<<32, 128, 0, stream>>>(feat, W1, bias);

    edge_main<64,  false><<<mg, 256, 0, stream>>>(feat, y, wt1, W1, 131, bias, nullptr, nullptr, ev, part);
    finalize<<<128, 256, 0, stream>>>(part, g1, b1, Aar, Car);

    bias0_next<<<32, 128, 0, stream>>>(y, Aar, Car, W2, bias);
    edge_main<128, true ><<<mg, 256, 0, stream>>>(y, y, wt2, W2, 259, bias, Aar, Car, ev, part);
    finalize<<<128, 256, 0, stream>>>(part, g2, b2, Aar, Car);

    bias0_next<<<32, 128, 0, stream>>>(y, Aar, Car, W3, bias);
    edge_main<128, true ><<<mg, 256, 0, stream>>>(y, y, wt3, W3, 259, bias, Aar, Car, ev, part);
    finalize<<<128, 256, 0, stream>>>(part, g3, b3, Aar, Car);

    bias0_next<<<32, 128, 0, stream>>>(y, Aar, Car, W4, bias);
    edge_main<128, true ><<<mg, 256, 0, stream>>>(y, y, wt4, W4, 259, bias, Aar, Car, ev, part);
    finalize<<<128, 256, 0, stream>>>(part, g4, b4, Aar, Car);

    maxout<<<1024, 256, 0, stream>>>(y, Aar, Car, (float*)d_out);
}

// Round 2
// 327.849 us; speedup vs baseline: 2.1144x; 2.1144x over previous
//
#include <hip/hip_runtime.h>
#include <string.h>

#define G 8192
#define B 32
#define O 128
#define NBLK 2048              // B * (G/128)
#define NTOT 262144.0f        // B*G

typedef float f32x4 __attribute__((ext_vector_type(4)));
typedef _Float16 half8 __attribute__((ext_vector_type(8)));
typedef _Float16 half4 __attribute__((ext_vector_type(4)));
typedef _Float16 half2v __attribute__((ext_vector_type(2)));

__device__ __forceinline__ float lrelu(float v) { return fmaxf(v, 0.1f * v); }

__device__ __forceinline__ unsigned pack2h(float lo, float hi) {
    half2v t; t.x = (_Float16)lo; t.y = (_Float16)hi;
    return __builtin_bit_cast(unsigned, t);
}

// ---- W fragment prep: layout [m8][kk][lane][j], o = m8*16+(lane&15),
//      k = kk*32 + (lane>>4)*4 + (j&3) + (j>>2)*16  (same mapping used for x staging)
__device__ __forceinline__ void wfrag_one(const float* __restrict__ W, int ldw, int K, int KS,
                                          _Float16* __restrict__ out, int idx) {
    int j = idx & 7, lane = (idx >> 3) & 63, t = idx >> 9;
    int kk = t % KS, m8 = t / KS;
    int o = m8 * 16 + (lane & 15);
    int k = kk * 32 + ((lane >> 4) & 3) * 4 + (j & 3) + (j >> 2) * 16;
    float v;
    if (k < K)          v = W[o * ldw + k] + W[o * ldw + K + k];
    else if (k < K + 3) v = W[o * ldw + 2 * K + (k - K)];
    else                v = 0.f;
    out[idx] = (_Float16)v;
}

__global__ void prep_all(const float* __restrict__ W1, const float* __restrict__ W2,
                         const float* __restrict__ W3, const float* __restrict__ W4,
                         _Float16* __restrict__ wf1, _Float16* __restrict__ wf2,
                         _Float16* __restrict__ wf3, _Float16* __restrict__ wf4) {
    int idx = blockIdx.x * 256 + threadIdx.x;
    if (idx < 12288)                wfrag_one(W1, 131, 64, 3, wf1, idx);
    else if (idx < 12288 + 20480)   wfrag_one(W2, 259, 128, 5, wf2, idx - 12288);
    else if (idx < 12288 + 40960)   wfrag_one(W3, 259, 128, 5, wf3, idx - 12288 - 20480);
    else if (idx < 12288 + 61440)   wfrag_one(W4, 259, 128, 5, wf4, idx - 12288 - 40960);
}

// bias0[b][o] = -sum_c Wb1[o][c] * features[b][c][0]
__global__ void bias0_first(const float* __restrict__ X, const float* __restrict__ W,
                            float* __restrict__ bias) {
    __shared__ float x0[64];
    int b = blockIdx.x, o = threadIdx.x;
    if (o < 64) x0[o] = X[((size_t)b * 64 + o) * G];
    __syncthreads();
    float acc = 0.f;
    for (int c = 0; c < 64; ++c) acc += W[o * 131 + 64 + c] * x0[c];
    bias[b * O + o] = -acc;
}

__global__ void bias0_next(const _Float16* __restrict__ Y, const float* __restrict__ A,
                           const float* __restrict__ Cc, const float* __restrict__ W,
                           float* __restrict__ bias) {
    __shared__ float xn[128];
    int b = blockIdx.x, o = threadIdx.x;
    float v = (float)Y[((size_t)b * O + o) * G];
    xn[o] = lrelu(A[o] * v + Cc[o]);
    __syncthreads();
    float acc = 0.f;
    for (int c = 0; c < 128; ++c) acc += W[o * 259 + 128 + c] * xn[c];
    bias[b * O + o] = -acc;
}

// ---- main layer kernel: tile O=128 x N=128 cols, K' = KS*32 (x rows + 3 ev rows + zero pad)
template<int K, int KS, bool NORM, bool F32IN>
__global__ __launch_bounds__(256) void edge_mfma(
    const void* __restrict__ Xin_,     // [B][K][G] f32 (layer1) or f16
    _Float16* __restrict__ Yout,       // [B][O][G] f16 raw (pre-BN)
    const _Float16* __restrict__ Wf,   // frag-major effective weights
    const float* __restrict__ bias,    // [B][O]
    const float* __restrict__ An, const float* __restrict__ Cn,
    const float* __restrict__ EV,      // [B][3][G] f32
    float* __restrict__ part)          // [NBLK][256]
{
    constexpr int KP  = KS * 32;
    constexpr int NHW = KS * 512 + 24;           // halfwords per n16 block (48B pad)
    static_assert(KP >= K + 3, "pad");
    __shared__ __align__(16) _Float16 lds[8 * NHW];

    const int tid  = threadIdx.x;
    const int lane = tid & 63;
    const int wave = tid >> 6;
    const int gt   = blockIdx.x;      // 0..63
    const int b    = blockIdx.y;      // 0..31
    const int g0   = gt * 128;
    const int bid  = b * 64 + gt;

    const float* Xf = (const float*)Xin_;
    const _Float16* Xh = (const _Float16*)Xin_;

    // ---- stage x_ext tile into LDS, fragment-major, 2 cols per thread
    {
        const int c0 = lane * 2;                 // cols c0, c0+1
        const int KGS = KP / 4;
        for (int kg = wave; kg < KGS; kg += 4) { // wave-uniform kg
            float va[4], vb[4];
            const int kbase = kg * 4;
            if (kbase < K) {
#pragma unroll
                for (int r = 0; r < 4; ++r) {
                    int k = kbase + r;
                    float x0, x1;
                    if (F32IN) {
                        const float* src = Xf + ((size_t)b * K + k) * G + g0 + c0;
                        x0 = src[0]; x1 = src[1];
                    } else {
                        const _Float16* src = Xh + ((size_t)b * K + k) * G + g0 + c0;
                        x0 = (float)src[0]; x1 = (float)src[1];
                    }
                    if (NORM) {
                        float a = An[k], cc = Cn[k];
                        x0 = lrelu(a * x0 + cc);
                        x1 = lrelu(a * x1 + cc);
                    }
                    va[r] = x0; vb[r] = x1;
                }
            } else {
#pragma unroll
                for (int r = 0; r < 4; ++r) {
                    int e = kbase + r - K;
                    if (e >= 0 && e < 3) {
                        const float* src = EV + ((size_t)b * 3 + e) * G + g0 + c0;
                        va[r] = src[0]; vb[r] = src[1];
                    } else { va[r] = 0.f; vb[r] = 0.f; }
                }
            }
            half4 ha, hb;
#pragma unroll
            for (int r = 0; r < 4; ++r) { ha[r] = (_Float16)va[r]; hb[r] = (_Float16)vb[r]; }
            const int kk = kg >> 3, jh = (kg >> 2) & 1, l16 = kg & 3;
            {
                int c = c0, q = c >> 3, n16 = c & 7;
                int off = n16 * NHW + kk * 512 + (q + l16 * 16) * 8 + jh * 4;
                *(half4*)(&lds[off]) = ha;
            }
            {
                int c = c0 + 1, q = c >> 3, n16 = c & 7;
                int off = n16 * NHW + kk * 512 + (q + l16 * 16) * 8 + jh * 4;
                *(half4*)(&lds[off]) = hb;
            }
        }
    }
    __syncthreads();

    // ---- A fragments from global (frag-major, 16B/lane, L2-hot)
    half8 af[2][KS];
#pragma unroll
    for (int m = 0; m < 2; ++m)
#pragma unroll
        for (int kk = 0; kk < KS; ++kk)
            af[m][kk] = *(const half8*)(Wf + (((wave * 2 + m) * KS + kk) * 64 + lane) * 8);

    f32x4 acc[2][8];
#pragma unroll
    for (int m = 0; m < 2; ++m)
#pragma unroll
        for (int n = 0; n < 8; ++n) acc[m][n] = (f32x4){0.f, 0.f, 0.f, 0.f};

#pragma unroll
    for (int kk = 0; kk < KS; ++kk) {
#pragma unroll
        for (int n = 0; n < 8; ++n) {
            half8 bf = *(const half8*)(&lds[n * NHW + kk * 512 + lane * 8]);
            acc[0][n] = __builtin_amdgcn_mfma_f32_16x16x32_f16(af[0][kk], bf, acc[0][n], 0, 0, 0);
            acc[1][n] = __builtin_amdgcn_mfma_f32_16x16x32_f16(af[1][kk], bf, acc[1][n], 0, 0, 0);
        }
    }

    // ---- epilogue: + bias0, stats partials, f16 store
    const int ob = wave * 32;
    const int fq = lane >> 4, fr = lane & 15;
#pragma unroll
    for (int m = 0; m < 2; ++m) {
        float4 bv = *(const float4*)(bias + b * O + ob + m * 16 + fq * 4);
#pragma unroll
        for (int n = 0; n < 8; ++n) {
            acc[m][n].x += bv.x; acc[m][n].y += bv.y;
            acc[m][n].z += bv.z; acc[m][n].w += bv.w;
        }
    }
#pragma unroll
    for (int m = 0; m < 2; ++m) {
#pragma unroll
        for (int i = 0; i < 4; ++i) {
            float s = 0.f, q = 0.f;
#pragma unroll
            for (int n = 0; n < 8; ++n) {
                float v = acc[m][n][i];
                s += v; q += v * v;
            }
            s += __shfl_xor(s, 1, 64); q += __shfl_xor(q, 1, 64);
            s += __shfl_xor(s, 2, 64); q += __shfl_xor(q, 2, 64);
            s += __shfl_xor(s, 4, 64); q += __shfl_xor(q, 4, 64);
            s += __shfl_xor(s, 8, 64); q += __shfl_xor(q, 8, 64);
            if (fr == 0) {
                int o = ob + m * 16 + fq * 4 + i;
                part[bid * 256 + o]       = s;
                part[bid * 256 + 128 + o] = q;
            }
            // store row o, 8 consecutive g = fr*8 + n
            uint4 w;
            w.x = pack2h(acc[m][0][i], acc[m][1][i]);
            w.y = pack2h(acc[m][2][i], acc[m][3][i]);
            w.z = pack2h(acc[m][4][i], acc[m][5][i]);
            w.w = pack2h(acc[m][6][i], acc[m][7][i]);
            size_t row = (size_t)b * O + ob + m * 16 + fq * 4 + i;
            *reinterpret_cast<uint4*>(Yout + row * G + g0 + fr * 8) = w;
        }
    }
}

// per-channel: reduce partials -> a = gamma*rsqrt(var+eps), c = beta - mean*a
__global__ void finalize(const float* __restrict__ part, const float* __restrict__ gamma,
                         const float* __restrict__ beta, float* __restrict__ A,
                         float* __restrict__ Cc) {
    __shared__ float rs[256], rq[256];
    int o = blockIdx.x, t = threadIdx.x;
    float s = 0.f, q = 0.f;
    for (int bid = t; bid < NBLK; bid += 256) {
        s += part[bid * 256 + o];
        q += part[bid * 256 + 128 + o];
    }
    rs[t] = s; rq[t] = q;
    __syncthreads();
    for (int w = 128; w > 0; w >>= 1) {
        if (t < w) { rs[t] += rs[t + w]; rq[t] += rq[t + w]; }
        __syncthreads();
    }
    if (t == 0) {
        float mean = rs[0] / NTOT;
        float var  = rq[0] / NTOT - mean * mean;
        float a = gamma[o] * rsqrtf(var + 1e-5f);
        A[o]  = a;
        Cc[o] = beta[o] - mean * a;
    }
}

// out[b][o] = max_g lrelu(a*y+c)
__global__ void maxout(const _Float16* __restrict__ Y, const float* __restrict__ A,
                       const float* __restrict__ Cc, float* __restrict__ out) {
    int w    = blockIdx.x * 4 + (threadIdx.x >> 6);
    int lane = threadIdx.x & 63;
    int b = w >> 7, o = w & 127;
    float a = A[o], cc = Cc[o];
    const _Float16* row = Y + ((size_t)b * O + o) * G;
    float m = -3.4e38f;
    for (int j = lane * 8; j < G; j += 512) {
        uint4 v = *reinterpret_cast<const uint4*>(row + j);
#pragma unroll
        for (int p = 0; p < 4; ++p) {
            unsigned u = (&v.x)[p];
            half2v h = __builtin_bit_cast(half2v, u);
            m = fmaxf(m, lrelu(a * (float)h.x + cc));
            m = fmaxf(m, lrelu(a * (float)h.y + cc));
        }
    }
    for (int d = 32; d > 0; d >>= 1) m = fmaxf(m, __shfl_down(m, d, 64));
    if (lane == 0) out[b * O + o] = m;
}

extern "C" void kernel_launch(void* const* d_in, const int* in_sizes, int n_in,
                              void* d_out, int out_size, void* d_ws, size_t ws_size,
                              hipStream_t stream) {
    const float* feat = (const float*)d_in[0];
    const float* ev   = (const float*)d_in[1];
    const float* W1   = (const float*)d_in[2];
    const float* W2   = (const float*)d_in[3];
    const float* W3   = (const float*)d_in[4];
    const float* W4   = (const float*)d_in[5];
    const float* g1   = (const float*)d_in[6];
    const float* b1   = (const float*)d_in[7];
    const float* g2   = (const float*)d_in[8];
    const float* b2   = (const float*)d_in[9];
    const float* g3   = (const float*)d_in[10];
    const float* b3   = (const float*)d_in[11];
    const float* g4   = (const float*)d_in[12];
    const float* b4   = (const float*)d_in[13];

    _Float16* y   = (_Float16*)d_ws;           // 33,554,432 halves (64 MB)
    _Float16* wf1 = y + 33554432;              // 12288
    _Float16* wf2 = wf1 + 12288;               // 20480
    _Float16* wf3 = wf2 + 20480;               // 20480
    _Float16* wf4 = wf3 + 20480;               // 20480
    float* bias = (float*)(wf4 + 20480);       // 4096
    float* Aar  = bias + 4096;                 // 128
    float* Car  = Aar + 128;                   // 128
    float* part = Car + 128;                   // 2048*256 floats (2 MB)

    dim3 mg(64, 32);
    prep_all<<<288, 256, 0, stream>>>(W1, W2, W3, W4, wf1, wf2, wf3, wf4);
    bias0_first<<<32, 128, 0, stream>>>(feat, W1, bias);

    edge_mfma<64, 3, false, true><<<mg, 256, 0, stream>>>(feat, y, wf1, bias, Aar, Car, ev, part);
    finalize<<<128, 256, 0, stream>>>(part, g1, b1, Aar, Car);

    bias0_next<<<32, 128, 0, stream>>>(y, Aar, Car, W2, bias);
    edge_mfma<128, 5, true, false><<<mg, 256, 0, stream>>>(y, y, wf2, bias, Aar, Car, ev, part);
    finalize<<<128, 256, 0, stream>>>(part, g2, b2, Aar, Car);

    bias0_next<<<32, 128, 0, stream>>>(y, Aar, Car, W3, bias);
    edge_mfma<128, 5, true, false><<<mg, 256, 0, stream>>>(y, y, wf3, bias, Aar, Car, ev, part);
    finalize<<<128, 256, 0, stream>>>(part, g3, b3, Aar, Car);

    bias0_next<<<32, 128, 0, stream>>>(y, Aar, Car, W4, bias);
    edge_mfma<128, 5, true, false><<<mg, 256, 0, stream>>>(y, y, wf4, bias, Aar, Car, ev, part);
    finalize<<<128, 256, 0, stream>>>(part, g4, b4, Aar, Car);

    maxout<<<1024, 256, 0, stream>>>(y, Aar, Car, (float*)d_out);
}